// Round 12
// baseline (168.760 us; speedup 1.0000x reference)
//
#include <hip/hip_runtime.h>
#include <hip/hip_bf16.h>
#include <cstdint>

typedef __attribute__((ext_vector_type(8))) short short8;
typedef __attribute__((ext_vector_type(4))) short bfx4;
typedef __attribute__((ext_vector_type(4))) float floatx4;

__device__ __forceinline__ float bf2f(unsigned short u) {
  union { unsigned int i; float f; } v;
  v.i = ((unsigned int)u) << 16;
  return v.f;
}
__device__ __forceinline__ unsigned short f2bf(float f) {
  union { float f; unsigned int i; } v; v.f = f;
  unsigned int r = v.i + 0x7FFFu + ((v.i >> 16) & 1u);
  return (unsigned short)(r >> 16);
}

__device__ __forceinline__ void async_copy16(const void* g, void* l) {
  __builtin_amdgcn_global_load_lds(
      (const __attribute__((address_space(1))) void*)g,
      (__attribute__((address_space(3))) void*)l, 16, 0, 0);
}

// ---------------------------------------------------------------------------
// Fused fp32->bf16 convert for x, qkv_w, proj_w in ONE launch.
// ---------------------------------------------------------------------------
__global__ __launch_bounds__(256) void convert3_kernel(
    const float* __restrict__ x, const float* __restrict__ w1,
    const float* __restrict__ w2, unsigned short* __restrict__ xb,
    unsigned short* __restrict__ w1b, unsigned short* __restrict__ w2b) {
  constexpr int N0 = 4096 * 512 / 8, N1 = 1536 * 512 / 8, N2 = 512 * 512 / 8;
  int i = blockIdx.x * 256 + threadIdx.x;
  const float* src;
  unsigned short* dst;
  int off;
  if (i < N0) { src = x; dst = xb; off = i; }
  else if (i < N0 + N1) { src = w1; dst = w1b; off = i - N0; }
  else if (i < N0 + N1 + N2) { src = w2; dst = w2b; off = i - N0 - N1; }
  else return;
  const float4* p = (const float4*)src + (size_t)off * 2;
  float4 a = p[0], b = p[1];
  short8 r;
  r[0] = (short)f2bf(a.x); r[1] = (short)f2bf(a.y);
  r[2] = (short)f2bf(a.z); r[3] = (short)f2bf(a.w);
  r[4] = (short)f2bf(b.x); r[5] = (short)f2bf(b.y);
  r[6] = (short)f2bf(b.z); r[7] = (short)f2bf(b.w);
  *(short8*)(dst + (size_t)off * 8) = r;
}

// ---------------------------------------------------------------------------
// Tiled GEMM (proven R3-R11): out = A @ W^T + bias, bf16 in, fp32 acc.
// FUSE_KV (gemm1 only): K tiles also write kt transposed; V tiles write only vt.
// ---------------------------------------------------------------------------
template <int BM, int BN, typename OutT, bool FUSE_KV>
__global__ __launch_bounds__(256) void gemm_tiled_kernel(
    const unsigned short* __restrict__ A, const unsigned short* __restrict__ W,
    const float* __restrict__ bias, OutT* __restrict__ out,
    int M, int N, int K,
    unsigned short* __restrict__ kt, unsigned short* __restrict__ vt) {
  constexpr int BK = 64;
  constexpr int MI = BM / 32;
  constexpr int NI = BN / 32;
  __shared__ __align__(16) unsigned short As[BM * BK];
  __shared__ __align__(16) unsigned short Ws[BN * BK];

  int tid = threadIdx.x, wave = tid >> 6, lane = tid & 63;
  int l16 = lane & 15, quad = lane >> 4;
  int bm = blockIdx.x, bn = blockIdx.y;
  int wm = (wave & 1) * (BM / 2), wn = (wave >> 1) * (BN / 2);

  floatx4 acc[MI][NI] = {};

  for (int kk = 0; kk < K; kk += BK) {
    __syncthreads();
#pragma unroll
    for (int c = 0; c < MI; c++) {
      int ci = (wave * MI + c) * 64 + lane;
      int row = ci >> 3, col8 = (ci & 7) ^ (row & 7);
      async_copy16(A + (size_t)(bm * BM + row) * K + kk + col8 * 8,
                   As + (size_t)ci * 8);
    }
#pragma unroll
    for (int c = 0; c < NI; c++) {
      int ci = (wave * NI + c) * 64 + lane;
      int row = ci >> 3, col8 = (ci & 7) ^ (row & 7);
      async_copy16(W + (size_t)(bn * BN + row) * K + kk + col8 * 8,
                   Ws + (size_t)ci * 8);
    }
    __syncthreads();

#pragma unroll
    for (int k2 = 0; k2 < 2; k2++) {
      short8 a[MI], w8[NI];
#pragma unroll
      for (int mi = 0; mi < MI; mi++) {
        int row = wm + mi * 16 + l16;
        int slot = ((k2 * 4 + quad) ^ (row & 7));
        a[mi] = *(const short8*)(As + row * 64 + slot * 8);
      }
#pragma unroll
      for (int ni = 0; ni < NI; ni++) {
        int row = wn + ni * 16 + l16;
        int slot = ((k2 * 4 + quad) ^ (row & 7));
        w8[ni] = *(const short8*)(Ws + row * 64 + slot * 8);
      }
#pragma unroll
      for (int mi = 0; mi < MI; mi++)
#pragma unroll
        for (int ni = 0; ni < NI; ni++)
          acc[mi][ni] = __builtin_amdgcn_mfma_f32_16x16x32_bf16(
              a[mi], w8[ni], acc[mi][ni], 0, 0, 0);
    }
  }

  int sec = 0, hh = 0;
  if constexpr (FUSE_KV) { sec = bn >> 3; hh = bn & 7; }

#pragma unroll
  for (int ni = 0; ni < NI; ni++) {
    int col = bn * BN + wn + ni * 16 + l16;
    float bb = bias[col];
#pragma unroll
    for (int mi = 0; mi < MI; mi++) {
      float v[4];
#pragma unroll
      for (int r = 0; r < 4; r++) v[r] = acc[mi][ni][r] + bb;
      int row0 = bm * BM + wm + mi * 16 + quad * 4;
      if constexpr (FUSE_KV) {
        if (sec >= 1) {  // K or V: transposed packed write
          bfx4 pk;
#pragma unroll
          for (int r = 0; r < 4; r++) pk[r] = (short)f2bf(v[r]);
          int d = col & 63;
          int bidx = row0 >> 11, n0 = row0 & 2047;
          unsigned short* dst = (sec == 1) ? kt : vt;
          *(bfx4*)(dst + ((size_t)((bidx * 8 + hh) * 64 + d)) * 2048 + n0) = pk;
        }
        if (sec <= 1) {  // Q or K: row-layout write (attn reads these)
#pragma unroll
          for (int r = 0; r < 4; r++)
            out[(size_t)(row0 + r) * N + col] = (OutT)f2bf(v[r]);
        }
      } else {
#pragma unroll
        for (int r = 0; r < 4; r++) {
          if constexpr (sizeof(OutT) == 2)
            out[(size_t)(row0 + r) * N + col] = (OutT)f2bf(v[r]);
          else
            out[(size_t)(row0 + r) * N + col] = (OutT)v[r];
        }
      }
    }
  }
}

// ---------------------------------------------------------------------------
// G partial: G[e][d] = sum_n K[n][e]K[n][d] over a 256-kv slice, from kt.
// ---------------------------------------------------------------------------
__global__ __launch_bounds__(256) void g_partial_kernel(
    const unsigned short* __restrict__ kt, float* __restrict__ gpart) {
  int bh = blockIdx.x, sl = blockIdx.y;
  int tid = threadIdx.x, wave = tid >> 6, lane = tid & 63;
  int l16 = lane & 15, quad = lane >> 4;
  const unsigned short* kb = kt + (size_t)bh * 64 * 2048;

  floatx4 acc[4] = {};
  for (int ks = 0; ks < 8; ks++) {
    int k0 = sl * 256 + ks * 32 + quad * 8;
    short8 a = *(const short8*)(kb + (size_t)(wave * 16 + l16) * 2048 + k0);
#pragma unroll
    for (int dt = 0; dt < 4; dt++) {
      short8 bb = *(const short8*)(kb + (size_t)(dt * 16 + l16) * 2048 + k0);
      acc[dt] = __builtin_amdgcn_mfma_f32_16x16x32_bf16(a, bb, acc[dt], 0, 0, 0);
    }
  }
  float* gout = gpart + ((size_t)(bh * 8 + sl)) * 4096;
#pragma unroll
  for (int dt = 0; dt < 4; dt++)
#pragma unroll
    for (int r = 0; r < 4; r++)
      gout[(wave * 16 + quad * 4 + r) * 64 + dt * 16 + l16] = acc[dt][r];
}

// Sum 8 slices -> bf16 G
__global__ __launch_bounds__(256) void g_reduce_kernel(
    const float* __restrict__ gpart, unsigned short* __restrict__ gb) {
  int i = blockIdx.x * 256 + threadIdx.x;  // < 16*4096
  int bh = i >> 12, ed = i & 4095;
  const float* p = gpart + (size_t)(bh * 8) * 4096 + ed;
  float s = 0.f;
#pragma unroll
  for (int j = 0; j < 8; j++) s += p[j * 4096];
  gb[i] = f2bf(s);
}

// ---------------------------------------------------------------------------
// Fused attention v7: 2-barrier pipelined chunk rhythm.
//  - K B-frags direct from global registers (R10-verified formula; each wave
//    only ever consumed its OWN staged K rows, so the LDS round-trip was a
//    no-op shuffle). Next chunk's bk loaded during current chunk (16 VGPRs
//    across barriers; plain launch_bounds — the ",4" hint caused R8/R9's
//    64-VGPR clamp + spill).
//  - Vtb DOUBLE-buffered (2x16KB) + Pb (8KB) = 40960 B, same 4 blk/CU as R6.
//  - Rhythm: barrier A -> [issue Vtb-next DMA + nbk loads] -> QK(reg) + exp +
//    P-write (no DS reads here) -> bk=nbk -> barrier B (drain lands ~a full
//    segment after issue -> overlapped) -> PV from Vtb[cur]+Pb.
// ---------------------------------------------------------------------------
__global__ __launch_bounds__(256) void attn_kernel(
    const unsigned short* __restrict__ qkv,
    const unsigned short* __restrict__ vt,
    const unsigned short* __restrict__ gb,
    unsigned short* __restrict__ attn_out) {
  constexpr int NSEQ = 2048, LD = 1536, DM = 512;
  const float scale = 0.125f;

  __shared__ __align__(16) unsigned short Vtb[2][64 * 128];  // [d][kv-slot^]
  __shared__ __align__(16) unsigned short Pb[32 * 128];      // [q][kv-slot^]

  int qb = blockIdx.x, h = blockIdx.y, b = blockIdx.z;
  int tid = threadIdx.x, wave = tid >> 6, lane = tid & 63;
  int l16 = lane & 15, quad = lane >> 4;

  const unsigned short* base = qkv + (size_t)b * NSEQ * LD;
  const unsigned short* vbase = vt + (size_t)(b * 8 + h) * 64 * NSEQ;

  // K B-frag base (R10-verified): rows wave*32 + st*16 + l16, cols quad*8
  const unsigned short* kp0 =
      base + (size_t)(wave * 32 + l16) * LD + 512 + h * 64 + quad * 8;

  // ---- stage chunk 0 (DMA Vtb[0] + bk regs), overlapped with prologue ----
#pragma unroll
  for (int c = 0; c < 4; c++) {
    int ci = (wave * 4 + c) * 64 + lane;
    int d = ci >> 4, sc = (ci & 15) ^ (d & 15);
    async_copy16(vbase + (size_t)d * NSEQ + 0 + sc * 8, &Vtb[0][0] + (size_t)ci * 8);
  }
  short8 bk[4];
#pragma unroll
  for (int st = 0; st < 2; st++)
#pragma unroll
    for (int k2 = 0; k2 < 2; k2++)
      bk[st * 2 + k2] = *(const short8*)(kp0 + (size_t)(st * 16) * LD + k2 * 32);

  // Q A-frags: 2 m-tiles of 16 q-rows
  short8 aq[2][2];
#pragma unroll
  for (int mi = 0; mi < 2; mi++) {
    const unsigned short* qp =
        base + (size_t)(qb * 32 + mi * 16 + l16) * LD + h * 64;
    aq[mi][0] = *(const short8*)(qp + quad * 8);
    aq[mi][1] = *(const short8*)(qp + 32 + quad * 8);
  }

  // ---------------- prologue: sumsq = q^T G q (proven R5-R11) ----------------
  const unsigned short* gbh = gb + (size_t)(b * 8 + h) * 4096;
  float sumsq[2][4] = {};
#pragma unroll
  for (int eti = 0; eti < 4; eti++) {
    floatx4 t[2] = {};
#pragma unroll
    for (int k2 = 0; k2 < 2; k2++) {
      short8 bg = *(const short8*)(gbh + (eti * 16 + l16) * 64 + k2 * 32 + quad * 8);
#pragma unroll
      for (int mi = 0; mi < 2; mi++)
        t[mi] = __builtin_amdgcn_mfma_f32_16x16x32_bf16(aq[mi][k2], bg, t[mi], 0, 0, 0);
    }
#pragma unroll
    for (int mi = 0; mi < 2; mi++)
#pragma unroll
      for (int r = 0; r < 4; r++) {
        float qv = bf2f(base[(size_t)(qb * 32 + mi * 16 + quad * 4 + r) * LD +
                             h * 64 + eti * 16 + l16]);
        sumsq[mi][r] += t[mi][r] * qv;
      }
  }
  float invk[2][4];
#pragma unroll
  for (int mi = 0; mi < 2; mi++)
#pragma unroll
    for (int r = 0; r < 4; r++) {
#pragma unroll
      for (int m = 1; m <= 8; m <<= 1)
        sumsq[mi][r] += __shfl_xor(sumsq[mi][r], m, 64);
      invk[mi][r] = scale / (scale * sqrtf(sumsq[mi][r]) + 1e-6f);
    }

  // ---------------- main loop: 2-barrier pipelined ----------------
  floatx4 o[2] = {};
  float lsum[2][4] = {};

  for (int mc = 0; mc < NSEQ; mc += 128) {
    int cur = (mc >> 7) & 1, nxt = cur ^ 1;
    __syncthreads();  // barrier A: prev PV readers done (Pb + Vtb[nxt])

    // issue next chunk's staging at segment top (drain overlaps QK segment)
    int mcn = (mc + 128 < NSEQ) ? mc + 128 : mc;
#pragma unroll
    for (int c = 0; c < 4; c++) {
      int ci = (wave * 4 + c) * 64 + lane;
      int d = ci >> 4, sc = (ci & 15) ^ (d & 15);
      async_copy16(vbase + (size_t)d * NSEQ + mcn + sc * 8,
                   &Vtb[nxt][0] + (size_t)ci * 8);
    }
    short8 nbk[4];
#pragma unroll
    for (int st = 0; st < 2; st++)
#pragma unroll
      for (int k2 = 0; k2 < 2; k2++)
        nbk[st * 2 + k2] =
            *(const short8*)(kp0 + (size_t)(mcn + st * 16) * LD + k2 * 32);

    // QK^T from registers + exp + P write (no DS reads in this segment)
#pragma unroll
    for (int st = 0; st < 2; st++) {
      floatx4 s[2] = {};
#pragma unroll
      for (int k2 = 0; k2 < 2; k2++)
#pragma unroll
        for (int mi = 0; mi < 2; mi++)
          s[mi] = __builtin_amdgcn_mfma_f32_16x16x32_bf16(
              aq[mi][k2], bk[st * 2 + k2], s[mi], 0, 0, 0);
      int kvc = wave * 4 + st * 2 + (l16 >> 3);
#pragma unroll
      for (int mi = 0; mi < 2; mi++)
#pragma unroll
        for (int r = 0; r < 4; r++) {
          float p = __expf(s[mi][r] * invk[mi][r]);
          lsum[mi][r] += p;
          int q = mi * 16 + quad * 4 + r;
          Pb[q * 128 + ((kvc ^ (q & 15)) << 3) + (l16 & 7)] = f2bf(p);
        }
    }
#pragma unroll
    for (int i = 0; i < 4; i++) bk[i] = nbk[i];

    __syncthreads();  // barrier B: P visible; staging drain (mostly retired)

    // PV: A-frags from Pb, B-frags from Vtb[cur]
    int d = wave * 16 + l16;
#pragma unroll
    for (int ks = 0; ks < 4; ks++) {
      short8 bv = *(const short8*)(&Vtb[cur][0] + d * 128 +
                                   (((ks * 4 + quad) ^ l16) * 8));
#pragma unroll
      for (int mi = 0; mi < 2; mi++) {
        int q = mi * 16 + l16;
        short8 ap = *(const short8*)(Pb + q * 128 +
                                     (((ks * 4 + quad) ^ (q & 15)) << 3));
        o[mi] = __builtin_amdgcn_mfma_f32_16x16x32_bf16(ap, bv, o[mi], 0, 0, 0);
      }
    }
  }
  __syncthreads();  // last PV reads done before Red reuses Pb

  // epilogue: lsum l16-reduce, cross-wave via Red (reuse Pb region)
#pragma unroll
  for (int mi = 0; mi < 2; mi++)
#pragma unroll
    for (int r = 0; r < 4; r++)
#pragma unroll
      for (int m = 1; m <= 8; m <<= 1)
        lsum[mi][r] += __shfl_xor(lsum[mi][r], m, 64);
  float* Red = (float*)Pb;  // [wave][32]
  if (l16 == 0) {
#pragma unroll
    for (int mi = 0; mi < 2; mi++)
#pragma unroll
      for (int r = 0; r < 4; r++)
        Red[wave * 32 + mi * 16 + quad * 4 + r] = lsum[mi][r];
  }
  __syncthreads();

  size_t ob = ((size_t)b * NSEQ + qb * 32) * DM + h * 64 + wave * 16 + l16;
#pragma unroll
  for (int mi = 0; mi < 2; mi++)
#pragma unroll
    for (int r = 0; r < 4; r++) {
      int q = mi * 16 + quad * 4 + r;
      float tot = Red[q] + Red[32 + q] + Red[64 + q] + Red[96 + q];
      attn_out[ob + (size_t)q * DM] = f2bf(o[mi][r] / tot);
    }
}

// ---------------------------------------------------------------------------
extern "C" void kernel_launch(void* const* d_in, const int* in_sizes, int n_in,
                              void* d_out, int out_size, void* d_ws, size_t ws_size,
                              hipStream_t stream) {
  const float* x = (const float*)d_in[0];
  const float* qkv_w = (const float*)d_in[1];
  const float* qkv_b = (const float*)d_in[2];
  const float* proj_w = (const float*)d_in[3];
  const float* proj_b = (const float*)d_in[4];
  float* out = (float*)d_out;

  unsigned short* xb = (unsigned short*)d_ws;             // 4096*512 (4MB)
  unsigned short* qkvw_b = xb + (size_t)4096 * 512;       // 1536*512 (1.5MB)
  unsigned short* projw_b = qkvw_b + (size_t)1536 * 512;  // 512*512
  unsigned short* qkv = projw_b + (size_t)512 * 512;      // 4096*1536 (12MB)
  unsigned short* attn_out = qkv + (size_t)4096 * 1536;   // 4096*512 (4MB)
  unsigned short* vt = attn_out + (size_t)4096 * 512;     // 16*64*2048 (4MB)
  unsigned short* gbuf = vt + (size_t)16 * 64 * 2048;     // 16*4096 bf16
  // Aliases (stream-ordered reuse):
  unsigned short* kt = attn_out;   // gemm1-written, g-read, dead before attn
  float* gpart = (float*)xb;       // 2MB <= 4MB; xb dead after gemm1

  // 0) fused fp32->bf16 converts
  convert3_kernel<<<1536, 256, 0, stream>>>(x, qkv_w, proj_w, xb, qkvw_b, projw_b);
  // 1) qkv = x @ qkv_w^T + qkv_b, with fused K/V transposed writes
  gemm_tiled_kernel<128, 64, unsigned short, true>
      <<<dim3(4096 / 128, 1536 / 64), 256, 0, stream>>>(
          xb, qkvw_b, qkv_b, qkv, 4096, 1536, 512, kt, vt);
  // 2) G = K^T K (8 partial slices in parallel, then reduce to bf16)
  g_partial_kernel<<<dim3(16, 8), 256, 0, stream>>>(kt, gpart);
  g_reduce_kernel<<<256, 256, 0, stream>>>(gpart, gbuf);
  // 3) fused attention (overwrites kt region with attn_out — g done by now)
  attn_kernel<<<dim3(64, 8, 2), 256, 0, stream>>>(qkv, vt, gbuf, attn_out);
  // 4) out = attn_out @ proj_w^T + proj_b
  gemm_tiled_kernel<64, 64, float, false>
      <<<dim3(4096 / 64, 512 / 64), 256, 0, stream>>>(
          attn_out, projw_b, proj_b, out, 4096, 512, 512, nullptr, nullptr);
}

// Round 13
// 144.174 us; speedup vs baseline: 1.1705x; 1.1705x over previous
//
#include <hip/hip_runtime.h>
#include <hip/hip_bf16.h>
#include <cstdint>

typedef __attribute__((ext_vector_type(8))) short short8;
typedef __attribute__((ext_vector_type(4))) short bfx4;
typedef __attribute__((ext_vector_type(4))) float floatx4;

__device__ __forceinline__ float bf2f(unsigned short u) {
  union { unsigned int i; float f; } v;
  v.i = ((unsigned int)u) << 16;
  return v.f;
}
__device__ __forceinline__ unsigned short f2bf(float f) {
  union { float f; unsigned int i; } v; v.f = f;
  unsigned int r = v.i + 0x7FFFu + ((v.i >> 16) & 1u);
  return (unsigned short)(r >> 16);
}

__device__ __forceinline__ void async_copy16(const void* g, void* l) {
  __builtin_amdgcn_global_load_lds(
      (const __attribute__((address_space(1))) void*)g,
      (__attribute__((address_space(3))) void*)l, 16, 0, 0);
}

// ---------------------------------------------------------------------------
// Fused fp32->bf16 convert for x, qkv_w, proj_w in ONE launch.
// ---------------------------------------------------------------------------
__global__ __launch_bounds__(256) void convert3_kernel(
    const float* __restrict__ x, const float* __restrict__ w1,
    const float* __restrict__ w2, unsigned short* __restrict__ xb,
    unsigned short* __restrict__ w1b, unsigned short* __restrict__ w2b) {
  constexpr int N0 = 4096 * 512 / 8, N1 = 1536 * 512 / 8, N2 = 512 * 512 / 8;
  int i = blockIdx.x * 256 + threadIdx.x;
  const float* src;
  unsigned short* dst;
  int off;
  if (i < N0) { src = x; dst = xb; off = i; }
  else if (i < N0 + N1) { src = w1; dst = w1b; off = i - N0; }
  else if (i < N0 + N1 + N2) { src = w2; dst = w2b; off = i - N0 - N1; }
  else return;
  const float4* p = (const float4*)src + (size_t)off * 2;
  float4 a = p[0], b = p[1];
  short8 r;
  r[0] = (short)f2bf(a.x); r[1] = (short)f2bf(a.y);
  r[2] = (short)f2bf(a.z); r[3] = (short)f2bf(a.w);
  r[4] = (short)f2bf(b.x); r[5] = (short)f2bf(b.y);
  r[6] = (short)f2bf(b.z); r[7] = (short)f2bf(b.w);
  *(short8*)(dst + (size_t)off * 8) = r;
}

// ---------------------------------------------------------------------------
// Tiled GEMM: out = A @ W^T + bias, bf16 in, fp32 acc.  BK templated:
// BK=128 halves the per-block barrier-drain count (8->4 K-iters); LDS grows
// to 48KB (gemm1) / 32KB (gemm2) but both grids are already CU-limited at
// 3 / 2 blocks per CU, so no occupancy loss (m132's regression was an
// occupancy cliff we don't hit).  CR = BK/8 16B-chunks per row; XOR swizzle
// (ci&(CR-1))^(row&(CR-1)) keeps column b128 reads at free 2-way.
// FUSE_KV (gemm1 only): K tiles also write kt transposed; V tiles write only
// vt (nothing reads V rows from qkv).
// ---------------------------------------------------------------------------
template <int BM, int BN, int BK, typename OutT, bool FUSE_KV>
__global__ __launch_bounds__(256) void gemm_tiled_kernel(
    const unsigned short* __restrict__ A, const unsigned short* __restrict__ W,
    const float* __restrict__ bias, OutT* __restrict__ out,
    int M, int N, int K,
    unsigned short* __restrict__ kt, unsigned short* __restrict__ vt) {
  constexpr int MI = BM / 32;
  constexpr int NI = BN / 32;
  constexpr int CR = BK / 8;       // 16B chunks per row
  constexpr int CA = BM * CR / 256;  // A-chunk loop count per wave
  constexpr int CW = BN * CR / 256;  // W-chunk loop count per wave
  __shared__ __align__(16) unsigned short As[BM * BK];
  __shared__ __align__(16) unsigned short Ws[BN * BK];

  int tid = threadIdx.x, wave = tid >> 6, lane = tid & 63;
  int l16 = lane & 15, quad = lane >> 4;
  int bm = blockIdx.x, bn = blockIdx.y;
  int wm = (wave & 1) * (BM / 2), wn = (wave >> 1) * (BN / 2);

  floatx4 acc[MI][NI] = {};

  for (int kk = 0; kk < K; kk += BK) {
    __syncthreads();
#pragma unroll
    for (int c = 0; c < CA; c++) {
      int ci = (wave * CA + c) * 64 + lane;
      int row = ci / CR, col8 = (ci & (CR - 1)) ^ (row & (CR - 1));
      async_copy16(A + (size_t)(bm * BM + row) * K + kk + col8 * 8,
                   As + (size_t)ci * 8);
    }
#pragma unroll
    for (int c = 0; c < CW; c++) {
      int ci = (wave * CW + c) * 64 + lane;
      int row = ci / CR, col8 = (ci & (CR - 1)) ^ (row & (CR - 1));
      async_copy16(W + (size_t)(bn * BN + row) * K + kk + col8 * 8,
                   Ws + (size_t)ci * 8);
    }
    __syncthreads();

#pragma unroll
    for (int k2 = 0; k2 < BK / 32; k2++) {
      short8 a[MI], w8[NI];
#pragma unroll
      for (int mi = 0; mi < MI; mi++) {
        int row = wm + mi * 16 + l16;
        int slot = ((k2 * 4 + quad) ^ (row & (CR - 1)));
        a[mi] = *(const short8*)(As + row * BK + slot * 8);
      }
#pragma unroll
      for (int ni = 0; ni < NI; ni++) {
        int row = wn + ni * 16 + l16;
        int slot = ((k2 * 4 + quad) ^ (row & (CR - 1)));
        w8[ni] = *(const short8*)(Ws + row * BK + slot * 8);
      }
#pragma unroll
      for (int mi = 0; mi < MI; mi++)
#pragma unroll
        for (int ni = 0; ni < NI; ni++)
          acc[mi][ni] = __builtin_amdgcn_mfma_f32_16x16x32_bf16(
              a[mi], w8[ni], acc[mi][ni], 0, 0, 0);
    }
  }

  int sec = 0, hh = 0;
  if constexpr (FUSE_KV) { sec = bn >> 3; hh = bn & 7; }

#pragma unroll
  for (int ni = 0; ni < NI; ni++) {
    int col = bn * BN + wn + ni * 16 + l16;
    float bb = bias[col];
#pragma unroll
    for (int mi = 0; mi < MI; mi++) {
      float v[4];
#pragma unroll
      for (int r = 0; r < 4; r++) v[r] = acc[mi][ni][r] + bb;
      int row0 = bm * BM + wm + mi * 16 + quad * 4;
      if constexpr (FUSE_KV) {
        if (sec >= 1) {  // K or V: transposed packed write
          bfx4 pk;
#pragma unroll
          for (int r = 0; r < 4; r++) pk[r] = (short)f2bf(v[r]);
          int d = col & 63;
          int bidx = row0 >> 11, n0 = row0 & 2047;
          unsigned short* dst = (sec == 1) ? kt : vt;
          *(bfx4*)(dst + ((size_t)((bidx * 8 + hh) * 64 + d)) * 2048 + n0) = pk;
        }
        if (sec <= 1) {  // Q or K: row-layout write (attn reads these)
#pragma unroll
          for (int r = 0; r < 4; r++)
            out[(size_t)(row0 + r) * N + col] = (OutT)f2bf(v[r]);
        }
      } else {
#pragma unroll
        for (int r = 0; r < 4; r++) {
          if constexpr (sizeof(OutT) == 2)
            out[(size_t)(row0 + r) * N + col] = (OutT)f2bf(v[r]);
          else
            out[(size_t)(row0 + r) * N + col] = (OutT)v[r];
        }
      }
    }
  }
}

// ---------------------------------------------------------------------------
// G partial: G[e][d] = sum_n K[n][e]K[n][d] over a 256-kv slice, from kt.
// ---------------------------------------------------------------------------
__global__ __launch_bounds__(256) void g_partial_kernel(
    const unsigned short* __restrict__ kt, float* __restrict__ gpart) {
  int bh = blockIdx.x, sl = blockIdx.y;
  int tid = threadIdx.x, wave = tid >> 6, lane = tid & 63;
  int l16 = lane & 15, quad = lane >> 4;
  const unsigned short* kb = kt + (size_t)bh * 64 * 2048;

  floatx4 acc[4] = {};
  for (int ks = 0; ks < 8; ks++) {
    int k0 = sl * 256 + ks * 32 + quad * 8;
    short8 a = *(const short8*)(kb + (size_t)(wave * 16 + l16) * 2048 + k0);
#pragma unroll
    for (int dt = 0; dt < 4; dt++) {
      short8 bb = *(const short8*)(kb + (size_t)(dt * 16 + l16) * 2048 + k0);
      acc[dt] = __builtin_amdgcn_mfma_f32_16x16x32_bf16(a, bb, acc[dt], 0, 0, 0);
    }
  }
  float* gout = gpart + ((size_t)(bh * 8 + sl)) * 4096;
#pragma unroll
  for (int dt = 0; dt < 4; dt++)
#pragma unroll
    for (int r = 0; r < 4; r++)
      gout[(wave * 16 + quad * 4 + r) * 64 + dt * 16 + l16] = acc[dt][r];
}

// Sum 8 slices -> bf16 G
__global__ __launch_bounds__(256) void g_reduce_kernel(
    const float* __restrict__ gpart, unsigned short* __restrict__ gb) {
  int i = blockIdx.x * 256 + threadIdx.x;  // < 16*4096
  int bh = i >> 12, ed = i & 4095;
  const float* p = gpart + (size_t)(bh * 8) * 4096 + ed;
  float s = 0.f;
#pragma unroll
  for (int j = 0; j < 8; j++) s += p[j * 4096];
  gb[i] = f2bf(s);
}

// ---------------------------------------------------------------------------
// Fused attention (R6/R11 verbatim — measured 54.4/54.8 us, VGPR 60,
// 0 conflicts; the all-DMA 3-barrier structure is the proven plateau:
// direct-global K/V variants regressed 4x in R5/R8/R9/R10/R12).
// ---------------------------------------------------------------------------
__global__ __launch_bounds__(256, 4) void attn_kernel(
    const unsigned short* __restrict__ qkv,
    const unsigned short* __restrict__ vt,
    const unsigned short* __restrict__ gb,
    unsigned short* __restrict__ attn_out) {
  constexpr int NSEQ = 2048, LD = 1536, DM = 512;
  const float scale = 0.125f;

  __shared__ __align__(16) unsigned short Kb[128 * 64];   // [kv][d-slot^]
  __shared__ __align__(16) unsigned short Vtb[64 * 128];  // [d][kv-slot^]
  __shared__ __align__(16) unsigned short Pb[32 * 128];   // [q][kv-slot^]

  int qb = blockIdx.x, h = blockIdx.y, b = blockIdx.z;
  int tid = threadIdx.x, wave = tid >> 6, lane = tid & 63;
  int l16 = lane & 15, quad = lane >> 4;

  const unsigned short* base = qkv + (size_t)b * NSEQ * LD;
  const unsigned short* vbase = vt + (size_t)(b * 8 + h) * 64 * NSEQ;

  // Q A-frags: 2 m-tiles of 16 q-rows
  short8 aq[2][2];
#pragma unroll
  for (int mi = 0; mi < 2; mi++) {
    const unsigned short* qp =
        base + (size_t)(qb * 32 + mi * 16 + l16) * LD + h * 64;
    aq[mi][0] = *(const short8*)(qp + quad * 8);
    aq[mi][1] = *(const short8*)(qp + 32 + quad * 8);
  }

  // ---------------- prologue: sumsq = q^T G q ----------------
  const unsigned short* gbh = gb + (size_t)(b * 8 + h) * 4096;
  float sumsq[2][4] = {};
#pragma unroll
  for (int eti = 0; eti < 4; eti++) {
    floatx4 t[2] = {};
#pragma unroll
    for (int k2 = 0; k2 < 2; k2++) {
      short8 bg = *(const short8*)(gbh + (eti * 16 + l16) * 64 + k2 * 32 + quad * 8);
#pragma unroll
      for (int mi = 0; mi < 2; mi++)
        t[mi] = __builtin_amdgcn_mfma_f32_16x16x32_bf16(aq[mi][k2], bg, t[mi], 0, 0, 0);
    }
#pragma unroll
    for (int mi = 0; mi < 2; mi++)
#pragma unroll
      for (int r = 0; r < 4; r++) {
        float qv = bf2f(base[(size_t)(qb * 32 + mi * 16 + quad * 4 + r) * LD +
                             h * 64 + eti * 16 + l16]);
        sumsq[mi][r] += t[mi][r] * qv;
      }
  }
  float invk[2][4];
#pragma unroll
  for (int mi = 0; mi < 2; mi++)
#pragma unroll
    for (int r = 0; r < 4; r++) {
#pragma unroll
      for (int m = 1; m <= 8; m <<= 1)
        sumsq[mi][r] += __shfl_xor(sumsq[mi][r], m, 64);
      invk[mi][r] = scale / (scale * sqrtf(sumsq[mi][r]) + 1e-6f);
    }

  // ---------------- main loop: softmax + PV ----------------
  floatx4 o[2] = {};
  float lsum[2][4] = {};

  for (int mc = 0; mc < NSEQ; mc += 128) {
    __syncthreads();  // prev chunk's Kb/Vtb/Pb readers done
#pragma unroll
    for (int c = 0; c < 4; c++) {  // K: [kv][d] swizzled
      int ci = (wave * 4 + c) * 64 + lane;
      int row = ci >> 3, sc = (ci & 7) ^ (row & 7);
      async_copy16(base + (size_t)(mc + row) * LD + 512 + h * 64 + sc * 8,
                   Kb + (size_t)ci * 8);
    }
#pragma unroll
    for (int c = 0; c < 4; c++) {  // Vt: [d][kv] swizzled
      int ci = (wave * 4 + c) * 64 + lane;
      int d = ci >> 4, sc = (ci & 15) ^ (d & 15);
      async_copy16(vbase + (size_t)d * NSEQ + mc + sc * 8,
                   Vtb + (size_t)ci * 8);
    }
    __syncthreads();  // staging complete (vmcnt(0) implied)

#pragma unroll
    for (int st = 0; st < 2; st++) {
      int row = wave * 32 + st * 16 + l16;  // chunk-local kv row
      floatx4 s[2] = {};
#pragma unroll
      for (int k2 = 0; k2 < 2; k2++) {
        short8 bk = *(const short8*)(Kb + row * 64 +
                                     (((k2 * 4 + quad) ^ (row & 7)) * 8));
#pragma unroll
        for (int mi = 0; mi < 2; mi++)
          s[mi] = __builtin_amdgcn_mfma_f32_16x16x32_bf16(aq[mi][k2], bk, s[mi], 0, 0, 0);
      }
      int kvc = wave * 4 + st * 2 + (l16 >> 3);
#pragma unroll
      for (int mi = 0; mi < 2; mi++)
#pragma unroll
        for (int r = 0; r < 4; r++) {
          float p = __expf(s[mi][r] * invk[mi][r]);
          lsum[mi][r] += p;
          int q = mi * 16 + quad * 4 + r;
          Pb[q * 128 + ((kvc ^ (q & 15)) << 3) + (l16 & 7)] = f2bf(p);
        }
    }
    __syncthreads();  // P visible to all waves

    int d = wave * 16 + l16;
#pragma unroll
    for (int ks = 0; ks < 4; ks++) {
      short8 bv = *(const short8*)(Vtb + d * 128 + (((ks * 4 + quad) ^ l16) * 8));
#pragma unroll
      for (int mi = 0; mi < 2; mi++) {
        int q = mi * 16 + l16;
        short8 ap = *(const short8*)(Pb + q * 128 + (((ks * 4 + quad) ^ (q & 15)) << 3));
        o[mi] = __builtin_amdgcn_mfma_f32_16x16x32_bf16(ap, bv, o[mi], 0, 0, 0);
      }
    }
  }
  __syncthreads();  // last PV reads done before Red reuses Pb

  // epilogue: lsum l16-reduce, cross-wave via Red (reuse Pb region)
#pragma unroll
  for (int mi = 0; mi < 2; mi++)
#pragma unroll
    for (int r = 0; r < 4; r++)
#pragma unroll
      for (int m = 1; m <= 8; m <<= 1)
        lsum[mi][r] += __shfl_xor(lsum[mi][r], m, 64);
  float* Red = (float*)Pb;  // [wave][32]
  if (l16 == 0) {
#pragma unroll
    for (int mi = 0; mi < 2; mi++)
#pragma unroll
      for (int r = 0; r < 4; r++)
        Red[wave * 32 + mi * 16 + quad * 4 + r] = lsum[mi][r];
  }
  __syncthreads();

  size_t ob = ((size_t)b * NSEQ + qb * 32) * DM + h * 64 + wave * 16 + l16;
#pragma unroll
  for (int mi = 0; mi < 2; mi++)
#pragma unroll
    for (int r = 0; r < 4; r++) {
      int q = mi * 16 + quad * 4 + r;
      float tot = Red[q] + Red[32 + q] + Red[64 + q] + Red[96 + q];
      attn_out[ob + (size_t)q * DM] = f2bf(o[mi][r] / tot);
    }
}

// ---------------------------------------------------------------------------
extern "C" void kernel_launch(void* const* d_in, const int* in_sizes, int n_in,
                              void* d_out, int out_size, void* d_ws, size_t ws_size,
                              hipStream_t stream) {
  const float* x = (const float*)d_in[0];
  const float* qkv_w = (const float*)d_in[1];
  const float* qkv_b = (const float*)d_in[2];
  const float* proj_w = (const float*)d_in[3];
  const float* proj_b = (const float*)d_in[4];
  float* out = (float*)d_out;

  unsigned short* xb = (unsigned short*)d_ws;             // 4096*512 (4MB)
  unsigned short* qkvw_b = xb + (size_t)4096 * 512;       // 1536*512 (1.5MB)
  unsigned short* projw_b = qkvw_b + (size_t)1536 * 512;  // 512*512
  unsigned short* qkv = projw_b + (size_t)512 * 512;      // 4096*1536 (12MB)
  unsigned short* attn_out = qkv + (size_t)4096 * 1536;   // 4096*512 (4MB)
  unsigned short* vt = attn_out + (size_t)4096 * 512;     // 16*64*2048 (4MB)
  unsigned short* gbuf = vt + (size_t)16 * 64 * 2048;     // 16*4096 bf16
  // Aliases (stream-ordered reuse):
  unsigned short* kt = attn_out;   // gemm1-written, g-read, dead before attn
  float* gpart = (float*)xb;       // 2MB <= 4MB; xb dead after gemm1

  // 0) fused fp32->bf16 converts
  convert3_kernel<<<1536, 256, 0, stream>>>(x, qkv_w, proj_w, xb, qkvw_b, projw_b);
  // 1) qkv = x @ qkv_w^T + qkv_b, fused K/V transposed writes, BK=128
  gemm_tiled_kernel<128, 64, 128, unsigned short, true>
      <<<dim3(4096 / 128, 1536 / 64), 256, 0, stream>>>(
          xb, qkvw_b, qkv_b, qkv, 4096, 1536, 512, kt, vt);
  // 2) G = K^T K (8 partial slices in parallel, then reduce to bf16)
  g_partial_kernel<<<dim3(16, 8), 256, 0, stream>>>(kt, gpart);
  g_reduce_kernel<<<256, 256, 0, stream>>>(gpart, gbuf);
  // 3) fused attention (overwrites kt region with attn_out — g done by now)
  attn_kernel<<<dim3(64, 8, 2), 256, 0, stream>>>(qkv, vt, gbuf, attn_out);
  // 4) out = attn_out @ proj_w^T + proj_b, BK=128
  gemm_tiled_kernel<64, 64, 128, float, false>
      <<<dim3(4096 / 64, 512 / 64), 256, 0, stream>>>(
          attn_out, projw_b, proj_b, out, 4096, 512, 512, nullptr, nullptr);
}